// Round 1
// baseline (1965.646 us; speedup 1.0000x reference)
//
#include <hip/hip_runtime.h>
#include <hip/hip_bf16.h>
#include <math.h>

// Problem constants (from reference):
//   embeddings [N_SUBDOCS=4096, N_WORDS=128, D=768] fp32
//   W [1,768], b [1], log_temperature [1], subdoc_lengths [N_DOCS=256] int32
//   out [N_DOCS] fp32
#define N_WORDS 128
#define DIM     768

// Kernel 1: one block per subdoc. Computes z[w] = dot(emb[n][w], W) + b,
// then softmax-pool over words: z_pool[n] = sum_w z*softmax(t*z).
__global__ __launch_bounds__(256) void subdoc_kernel(
    const float* __restrict__ emb,
    const float* __restrict__ W,
    const float* __restrict__ b,
    const float* __restrict__ logt,
    float* __restrict__ z_pool)
{
    const int n    = blockIdx.x;
    const int tid  = threadIdx.x;
    const int lane = tid & 63;
    const int wave = tid >> 6;        // 0..3

    // W held in registers: lane i owns W4[i], W4[i+64], W4[i+128] (192 float4 total)
    const float4* W4 = (const float4*)W;
    const float4 w0 = W4[lane];
    const float4 w1 = W4[lane + 64];
    const float4 w2 = W4[lane + 128];
    const float  bb = b[0];

    __shared__ float zsh[N_WORDS];

    const float4* e4 = (const float4*)(emb + (size_t)n * (N_WORDS * DIM));

    // each wave handles 32 contiguous words
    #pragma unroll 4
    for (int wi = 0; wi < 32; ++wi) {
        const int word = wave * 32 + wi;
        const float4* row = e4 + (size_t)word * (DIM / 4);
        const float4 e0 = row[lane];        // coalesced: 1 KB per wave per load
        const float4 e1 = row[lane + 64];
        const float4 e2 = row[lane + 128];
        float s = e0.x*w0.x + e0.y*w0.y + e0.z*w0.z + e0.w*w0.w
                + e1.x*w1.x + e1.y*w1.y + e1.z*w1.z + e1.w*w1.w
                + e2.x*w2.x + e2.y*w2.y + e2.z*w2.z + e2.w*w2.w;
        // wave-64 reduce
        #pragma unroll
        for (int off = 32; off > 0; off >>= 1)
            s += __shfl_down(s, off);
        if (lane == 0) zsh[word] = s + bb;
    }
    __syncthreads();

    // wave 0: softmax-pool over 128 words (2 per lane)
    if (wave == 0) {
        const float t = expf(logt[0]);
        const float z0 = zsh[lane];
        const float z1 = zsh[lane + 64];
        const float a0 = t * z0, a1 = t * z1;
        float m = fmaxf(a0, a1);
        #pragma unroll
        for (int off = 32; off > 0; off >>= 1)
            m = fmaxf(m, __shfl_xor(m, off));
        const float p0 = expf(a0 - m);
        const float p1 = expf(a1 - m);
        float num = z0 * p0 + z1 * p1;
        float den = p0 + p1;
        #pragma unroll
        for (int off = 32; off > 0; off >>= 1) {
            num += __shfl_xor(num, off);
            den += __shfl_xor(den, off);
        }
        if (lane == 0) z_pool[n] = num / den;
    }
}

// Kernel 2: one thread per doc. Ragged segment softmax-pool over subdocs + sigmoid.
__global__ __launch_bounds__(256) void doc_kernel(
    const float* __restrict__ z_pool,
    const int* __restrict__ lens,
    const float* __restrict__ logt,
    float* __restrict__ out,
    int n_docs)
{
    __shared__ int slens[1024];
    const int d = threadIdx.x;
    if (d < n_docs) slens[d] = lens[d];
    __syncthreads();
    if (d >= n_docs) return;

    int start = 0;
    for (int i = 0; i < d; ++i) start += slens[i];
    const int len = slens[d];

    const float t = expf(logt[0]);

    float m = -INFINITY;
    for (int i = 0; i < len; ++i)
        m = fmaxf(m, t * z_pool[start + i]);

    float num = 0.f, den = 0.f;
    for (int i = 0; i < len; ++i) {
        const float z = z_pool[start + i];
        const float e = expf(t * z - m);
        num += z * e;
        den += e;
    }
    const float x = num / den;
    out[d] = 1.0f / (1.0f + expf(-x));
}

extern "C" void kernel_launch(void* const* d_in, const int* in_sizes, int n_in,
                              void* d_out, int out_size, void* d_ws, size_t ws_size,
                              hipStream_t stream)
{
    const float* emb  = (const float*)d_in[0];
    const float* W    = (const float*)d_in[1];
    const float* b    = (const float*)d_in[2];
    const float* logt = (const float*)d_in[3];
    const int*   lens = (const int*)d_in[4];
    float*       out  = (float*)d_out;
    float*       z_pool = (float*)d_ws;   // n_subdocs floats (16 KB)

    const int n_subdocs = in_sizes[0] / (N_WORDS * DIM);   // 4096
    const int n_docs    = in_sizes[4];                     // 256

    subdoc_kernel<<<n_subdocs, 256, 0, stream>>>(emb, W, b, logt, z_pool);
    doc_kernel<<<1, 256, 0, stream>>>(z_pool, lens, logt, out, n_docs);
}